// Round 6
// baseline (223.551 us; speedup 1.0000x reference)
//
#include <hip/hip_runtime.h>
#include <cstdint>

// Problem constants
#define C_IN   128
#define C_OUT  256
#define KK     1152      // C_IN * 9 (im2col K)
#define NPIX   4096      // 64*64
#define BS     16
#define M_ROWS 65536     // BS * NPIX
#define QMAXF  127.0f

typedef int v4i __attribute__((ext_vector_type(4)));

// ---- workspace layout (bytes) ----
// qW' (tap-major permuted) @ OFF_QW; w_part aliases it (read before qW' write).
#define OFF_QW    75497472
#define OFF_SCALE 75792384
#define OFF_QMUL  75796992
#define OFF_APART 75801600
#define OFF_SCAL  75843072

// K-A: fused act_scale (blocks 0..1023) + w_scale (blocks 1024..1103).
__global__ void k_prep(const float* __restrict__ x, const float* __restrict__ wgt,
                       float* __restrict__ act_part, float* __restrict__ w_part) {
    const int tid = threadIdx.x;
    if (blockIdx.x >= 1024) {
        int t = blockIdx.x - 1024;        // 0..79
        int j = (t % 5) * 256 + tid;
        int s = t / 5;                    // 0..15
        if (j >= KK) return;
        const float* p = wgt + (size_t)s * 16 * KK + j;
        float m = 0.f;
#pragma unroll
        for (int i = 0; i < 16; i++) m = fmaxf(m, fabsf(p[(size_t)i * KK]));
        w_part[s * KK + j] = m;
        return;
    }
    const int c = blockIdx.x >> 3, s = blockIdx.x & 7;
    float m[9];
#pragma unroll
    for (int i = 0; i < 9; i++) m[i] = 0.f;
    for (int p = tid; p < 2 * NPIX; p += 256) {
        int b = s * 2 + (p >> 12);
        int hw = p & 4095;
        int h = hw >> 6, w = hw & 63;
        float v = fabsf(x[b * (C_IN * NPIX) + c * NPIX + hw]);
        bool rr[3] = { h <= 62, true, h >= 1 };
        bool cc[3] = { w <= 62, true, w >= 1 };
#pragma unroll
        for (int i = 0; i < 3; i++)
#pragma unroll
            for (int jq = 0; jq < 3; jq++)
                m[i * 3 + jq] = fmaxf(m[i * 3 + jq], (rr[i] && cc[jq]) ? v : 0.f);
    }
    __shared__ float sm[9][4];
    int lane = tid & 63, wid = tid >> 6;
#pragma unroll
    for (int i = 0; i < 9; i++) {
        float v = m[i];
        for (int off = 32; off > 0; off >>= 1) v = fmaxf(v, __shfl_down(v, off));
        if (lane == 0) sm[i][wid] = v;
    }
    __syncthreads();
    if (tid < 9) {
        float v = fmaxf(fmaxf(sm[tid][0], sm[tid][1]), fmaxf(sm[tid][2], sm[tid][3]));
        act_part[s * KK + c * 9 + tid] = v;
    }
}

// K-B: scales + s_x + s_w + qmul. Single block, 1024 threads.
__global__ void k_scales(const float* __restrict__ act_part, const float* __restrict__ w_part,
                         float* __restrict__ scale, float* __restrict__ qmul,
                         float* __restrict__ scalars) {
    const int tid = threadIdx.x;
    float sc_local[2] = {1.f, 1.f};
    float mx = 0.f, mw = 0.f;
#pragma unroll
    for (int t = 0; t < 2; t++) {
        int j = tid + t * 1024;
        if (j < KK) {
            float a = 0.f;
#pragma unroll
            for (int s = 0; s < 8; s++) a = fmaxf(a, act_part[s * KK + j]);
            float wv = 0.f;
#pragma unroll
            for (int s = 0; s < 16; s++) wv = fmaxf(wv, w_part[s * KK + j]);
            float sc = sqrtf(a) / sqrtf(wv);
            if (sc == 0.f) sc = 1.0f;
            scale[j] = sc;
            sc_local[t] = sc;
            mx = fmaxf(mx, a / sc);    // exact: max_r |cols[r,j]/sc| == fl(act/sc)
            mw = fmaxf(mw, wv * sc);   // exact: max_i |w2[i,j]*sc|  == fl(wsc*sc)
        }
    }
    __shared__ float smx[16], smw[16];
    __shared__ float s_x_sh;
    int lane = tid & 63, wid = tid >> 6;
    for (int off = 32; off > 0; off >>= 1) {
        mx = fmaxf(mx, __shfl_down(mx, off));
        mw = fmaxf(mw, __shfl_down(mw, off));
    }
    if (lane == 0) { smx[wid] = mx; smw[wid] = mw; }
    __syncthreads();
    if (tid == 0) {
        float a = 0.f, b = 0.f;
        for (int i = 0; i < 16; i++) { a = fmaxf(a, smx[i]); b = fmaxf(b, smw[i]); }
        float s_x = a / QMAXF; if (s_x == 0.f) s_x = 1.f;
        float s_w = b / QMAXF; if (s_w == 0.f) s_w = 1.f;
        scalars[0] = s_x; scalars[1] = s_w; scalars[2] = s_x * s_w;
        s_x_sh = s_x;
    }
    __syncthreads();
    float s_x = s_x_sh;
#pragma unroll
    for (int t = 0; t < 2; t++) {
        int j = tid + t * 1024;
        if (j < KK) qmul[j] = 1.0f / (sc_local[t] * s_x);
    }
}

// K-C: quantize weights into TAP-MAJOR layout: qWp[m][tap*128 + c] = fq(w[m][c*9+tap]).
__global__ void k_quant_w(const float* __restrict__ wgt, const float* __restrict__ scale,
                          const float* __restrict__ scalars, signed char* __restrict__ qWp) {
    int idx = blockIdx.x * 256 + threadIdx.x;   // < 294912, coalesced WRITE
    int m  = (unsigned)idx / KK;
    int kp = idx - m * KK;
    int tap = kp >> 7, c = kp & 127;
    int j = c * 9 + tap;                        // original k index
    float s_w = scalars[1];
    float t = wgt[m * KK + j] * scale[j];
    float q = rintf(t / s_w);
    q = fminf(fmaxf(q, -QMAXF), QMAXF);
    qWp[idx] = (signed char)(int)q;
}

// ---- fused GEMM helpers ----
__device__ __forceinline__ void load_xv(const float* __restrict__ xb, int oh, int tap,
                                        int lane, int c0a, int c0b, float* xv) {
    const int kh = (tap * 11) >> 5;       // tap/3 for 0..8
    const int kw = tap - kh * 3;
    const int ih = oh + kh - 1;           // block-uniform
    const int iw = lane + kw - 1;
    const bool ok = ((unsigned)ih < 64u) && ((unsigned)iw < 64u);
    const float* s = xb + ih * 64 + iw;
#pragma unroll
    for (int d = 0; d < 16; d++) xv[d]      = ok ? s[(size_t)(c0a + d) * NPIX] : 0.f;
#pragma unroll
    for (int d = 0; d < 16; d++) xv[16 + d] = ok ? s[(size_t)(c0b + d) * NPIX] : 0.f;
}

__device__ __forceinline__ void load_af(const signed char* __restrict__ aBase, int tap,
                                        v4i af[2][4]) {
#pragma unroll
    for (int h = 0; h < 2; h++)
#pragma unroll
        for (int mt = 0; mt < 4; mt++)
            af[h][mt] = *(const v4i*)(aBase + (size_t)mt * 16 * KK + tap * 128 + h * 64);
}

// K-D: FUSED quant+GEMM v2, register-pipelined. Block = 256(M) x 64(N = 1 out row).
// 256 thr, 4 waves (one 64-row M-strip each). A-fragments: global->VGPR direct
// (qWp is L2-hot, 288 KB), prefetched one tap ahead. B: x loads prefetched one tap
// ahead into VGPRs, quantized+packed -> double-buffered Bs (XOR 16B-chunk swizzle).
// One barrier per tap.
__global__ __launch_bounds__(256, 2) void k_gemm(const signed char* __restrict__ qWp,
                                                 const float* __restrict__ x,
                                                 const float* __restrict__ qmul,
                                                 const float* __restrict__ scalars,
                                                 const float* __restrict__ bias,
                                                 float* __restrict__ out) {
    __shared__ __align__(16) signed char Bs[2][64 * 128];  // 2 x 8 KB
    __shared__ float qm[KK];                               // permuted qmul [tap][c]
    const int tid = threadIdx.x;
    const int lane = tid & 63, wv = tid >> 6;              // 4 waves, wm = wv
    const int b  = blockIdx.x >> 6;
    const int oh = blockIdx.x & 63;                        // out row
    const float* xb = x + (size_t)b * (C_IN * NPIX);

    for (int i = tid; i < KK; i += 256) {
        int tap = i >> 7, c = i & 127;
        qm[i] = qmul[c * 9 + tap];
    }

    // A addressing: row = wv*64 + mt*16 + (lane&15); chunk = (h*4 + lane>>4)*16
    const signed char* aBase = qWp + (size_t)(wv * 64 + (lane & 15)) * KK + (lane >> 4) * 16;
    // B producer: this thread covers pixel `lane`, chunks {wv, wv+4} (16 ch each)
    const int c0a = wv * 16, c0b = (wv + 4) * 16;
    const int swz = lane & 7;

    v4i acc[4][4];
#pragma unroll
    for (int i = 0; i < 4; i++)
#pragma unroll
        for (int jq = 0; jq < 4; jq++) acc[i][jq] = (v4i){0, 0, 0, 0};

    // prefetch tap 0
    v4i af[2][4];
    float xv[32];
    load_af(aBase, 0, af);
    load_xv(xb, oh, 0, lane, c0a, c0b, xv);

    __syncthreads();   // qm ready

#pragma unroll
    for (int tap = 0; tap < 9; tap++) {
        signed char* bsp = Bs[tap & 1];
        // ---- produce Bs from prefetched xv ----
        const float* qmt = qm + tap * 128;
        int pk[8];
#pragma unroll
        for (int d = 0; d < 8; d++) {
            int w = 0;
            int cbase = (d < 4) ? (c0a + d * 4) : (c0b + (d - 4) * 4);
#pragma unroll
            for (int e = 0; e < 4; e++) {
                float q = rintf(xv[d * 4 + e] * qmt[cbase + e]);
                q = fminf(fmaxf(q, -QMAXF), QMAXF);
                w |= ((int)q & 255) << (8 * e);
            }
            pk[d] = w;
        }
        *(v4i*)(bsp + lane * 128 + ((wv ^ swz) * 16))       = (v4i){pk[0], pk[1], pk[2], pk[3]};
        *(v4i*)(bsp + lane * 128 + (((wv + 4) ^ swz) * 16)) = (v4i){pk[4], pk[5], pk[6], pk[7]};
        __syncthreads();   // Bs[tap&1] ready (single barrier per tap; dbuf covers WAR)

        // ---- prefetch next tap (overlaps MFMA below) ----
        v4i afn[2][4];
        float xvn[32];
        if (tap < 8) {
            load_af(aBase, tap + 1, afn);
            load_xv(xb, oh, tap + 1, lane, c0a, c0b, xvn);
        }

        // ---- MFMA: two K=64 substeps ----
#pragma unroll
        for (int h = 0; h < 2; h++) {
            const int q4 = h * 4 + (lane >> 4);
            v4i bf[4];
#pragma unroll
            for (int nt = 0; nt < 4; nt++) {
                int rb = nt * 16 + (lane & 15);
                bf[nt] = *(const v4i*)(bsp + rb * 128 + ((q4 ^ (rb & 7)) * 16));
            }
#pragma unroll
            for (int mt = 0; mt < 4; mt++)
#pragma unroll
                for (int nt = 0; nt < 4; nt++)
                    acc[mt][nt] = __builtin_amdgcn_mfma_i32_16x16x64_i8(af[h][mt], bf[nt], acc[mt][nt], 0, 0, 0);
        }

        // rotate prefetch buffers (register renaming under full unroll)
        if (tap < 8) {
#pragma unroll
            for (int h = 0; h < 2; h++)
#pragma unroll
                for (int mt = 0; mt < 4; mt++) af[h][mt] = afn[h][mt];
#pragma unroll
            for (int i = 0; i < 32; i++) xv[i] = xvn[i];
        }
    }

    const float ssp = scalars[2];
    const int quad = lane >> 4, col = lane & 15;
    float bv[4][4];
#pragma unroll
    for (int mt = 0; mt < 4; mt++)
#pragma unroll
        for (int rg = 0; rg < 4; rg++)
            bv[mt][rg] = bias[wv * 64 + mt * 16 + quad * 4 + rg];

    float* obase = out + ((size_t)b * C_OUT) * NPIX + oh * 64;
#pragma unroll
    for (int mt = 0; mt < 4; mt++) {
#pragma unroll
        for (int nt = 0; nt < 4; nt++) {
            int n = nt * 16 + col;                           // pixel in row
#pragma unroll
            for (int rg = 0; rg < 4; rg++) {
                int m = wv * 64 + mt * 16 + quad * 4 + rg;   // c_out
                obase[(size_t)m * NPIX + n] = (float)acc[mt][nt][rg] * ssp + bv[mt][rg];
            }
        }
    }
}

extern "C" void kernel_launch(void* const* d_in, const int* in_sizes, int n_in,
                              void* d_out, int out_size, void* d_ws, size_t ws_size,
                              hipStream_t stream) {
    const float* x    = (const float*)d_in[0];
    const float* wgt  = (const float*)d_in[1];
    const float* bias = (const float*)d_in[2];
    float* out = (float*)d_out;

    char* ws = (char*)d_ws;
    signed char* qWp = (signed char*)(ws + OFF_QW);
    float* w_part    = (float*)(ws + OFF_QW);     // aliases qWp (read before qWp write)
    float* scale     = (float*)(ws + OFF_SCALE);
    float* qmul      = (float*)(ws + OFF_QMUL);
    float* act_part  = (float*)(ws + OFF_APART);
    float* scalars   = (float*)(ws + OFF_SCAL);

    k_prep<<<1104, 256, 0, stream>>>(x, wgt, act_part, w_part);
    k_scales<<<1, 1024, 0, stream>>>(act_part, w_part, scale, qmul, scalars);
    k_quant_w<<<(C_OUT * KK) / 256, 256, 0, stream>>>(wgt, scale, scalars, qWp);
    k_gemm<<<BS * 64, 256, 0, stream>>>(qWp, x, qmul, scalars, bias, out);
}

// Round 7
// 155.501 us; speedup vs baseline: 1.4376x; 1.4376x over previous
//
#include <hip/hip_runtime.h>
#include <cstdint>

// Problem constants
#define C_IN   128
#define C_OUT  256
#define KK     1152      // C_IN * 9 (im2col K)
#define NPIX   4096      // 64*64
#define BS     16
#define M_ROWS 65536     // BS * NPIX
#define QMAXF  127.0f

typedef int v4i __attribute__((ext_vector_type(4)));

// ---- workspace layout (bytes) ----
// qW' (tap-major permuted) @ OFF_QW; w_part aliases it (read before qW' write).
#define OFF_QW    75497472
#define OFF_SCALE 75792384
#define OFF_QMUL  75796992
#define OFF_APART 75801600
#define OFF_SCAL  75843072

// K-A: fused act_scale (blocks 0..1023) + w_scale (blocks 1024..1103).
__global__ void k_prep(const float* __restrict__ x, const float* __restrict__ wgt,
                       float* __restrict__ act_part, float* __restrict__ w_part) {
    const int tid = threadIdx.x;
    if (blockIdx.x >= 1024) {
        int t = blockIdx.x - 1024;        // 0..79
        int j = (t % 5) * 256 + tid;
        int s = t / 5;                    // 0..15
        if (j >= KK) return;
        const float* p = wgt + (size_t)s * 16 * KK + j;
        float m = 0.f;
#pragma unroll
        for (int i = 0; i < 16; i++) m = fmaxf(m, fabsf(p[(size_t)i * KK]));
        w_part[s * KK + j] = m;
        return;
    }
    const int c = blockIdx.x >> 3, s = blockIdx.x & 7;
    float m[9];
#pragma unroll
    for (int i = 0; i < 9; i++) m[i] = 0.f;
    for (int p = tid; p < 2 * NPIX; p += 256) {
        int b = s * 2 + (p >> 12);
        int hw = p & 4095;
        int h = hw >> 6, w = hw & 63;
        float v = fabsf(x[b * (C_IN * NPIX) + c * NPIX + hw]);
        bool rr[3] = { h <= 62, true, h >= 1 };
        bool cc[3] = { w <= 62, true, w >= 1 };
#pragma unroll
        for (int i = 0; i < 3; i++)
#pragma unroll
            for (int jq = 0; jq < 3; jq++)
                m[i * 3 + jq] = fmaxf(m[i * 3 + jq], (rr[i] && cc[jq]) ? v : 0.f);
    }
    __shared__ float sm[9][4];
    int lane = tid & 63, wid = tid >> 6;
#pragma unroll
    for (int i = 0; i < 9; i++) {
        float v = m[i];
        for (int off = 32; off > 0; off >>= 1) v = fmaxf(v, __shfl_down(v, off));
        if (lane == 0) sm[i][wid] = v;
    }
    __syncthreads();
    if (tid < 9) {
        float v = fmaxf(fmaxf(sm[tid][0], sm[tid][1]), fmaxf(sm[tid][2], sm[tid][3]));
        act_part[s * KK + c * 9 + tid] = v;
    }
}

// K-B: scales + s_x + s_w + qmul. Single block, 1024 threads.
__global__ void k_scales(const float* __restrict__ act_part, const float* __restrict__ w_part,
                         float* __restrict__ scale, float* __restrict__ qmul,
                         float* __restrict__ scalars) {
    const int tid = threadIdx.x;
    float sc_local[2] = {1.f, 1.f};
    float mx = 0.f, mw = 0.f;
#pragma unroll
    for (int t = 0; t < 2; t++) {
        int j = tid + t * 1024;
        if (j < KK) {
            float a = 0.f;
#pragma unroll
            for (int s = 0; s < 8; s++) a = fmaxf(a, act_part[s * KK + j]);
            float wv = 0.f;
#pragma unroll
            for (int s = 0; s < 16; s++) wv = fmaxf(wv, w_part[s * KK + j]);
            float sc = sqrtf(a) / sqrtf(wv);
            if (sc == 0.f) sc = 1.0f;
            scale[j] = sc;
            sc_local[t] = sc;
            mx = fmaxf(mx, a / sc);    // exact: max_r |cols[r,j]/sc| == fl(act/sc)
            mw = fmaxf(mw, wv * sc);   // exact: max_i |w2[i,j]*sc|  == fl(wsc*sc)
        }
    }
    __shared__ float smx[16], smw[16];
    __shared__ float s_x_sh;
    int lane = tid & 63, wid = tid >> 6;
    for (int off = 32; off > 0; off >>= 1) {
        mx = fmaxf(mx, __shfl_down(mx, off));
        mw = fmaxf(mw, __shfl_down(mw, off));
    }
    if (lane == 0) { smx[wid] = mx; smw[wid] = mw; }
    __syncthreads();
    if (tid == 0) {
        float a = 0.f, b = 0.f;
        for (int i = 0; i < 16; i++) { a = fmaxf(a, smx[i]); b = fmaxf(b, smw[i]); }
        float s_x = a / QMAXF; if (s_x == 0.f) s_x = 1.f;
        float s_w = b / QMAXF; if (s_w == 0.f) s_w = 1.f;
        scalars[0] = s_x; scalars[1] = s_w; scalars[2] = s_x * s_w;
        s_x_sh = s_x;
    }
    __syncthreads();
    float s_x = s_x_sh;
#pragma unroll
    for (int t = 0; t < 2; t++) {
        int j = tid + t * 1024;
        if (j < KK) qmul[j] = 1.0f / (sc_local[t] * s_x);
    }
}

// K-C: quantize weights into TAP-MAJOR layout: qWp[m][tap*128 + c] = fq(w[m][c*9+tap]).
__global__ void k_quant_w(const float* __restrict__ wgt, const float* __restrict__ scale,
                          const float* __restrict__ scalars, signed char* __restrict__ qWp) {
    int idx = blockIdx.x * 256 + threadIdx.x;   // < 294912, coalesced WRITE
    int m  = (unsigned)idx / KK;
    int kp = idx - m * KK;
    int tap = kp >> 7, c = kp & 127;
    int j = c * 9 + tap;                        // original k index
    float s_w = scalars[1];
    float t = wgt[m * KK + j] * scale[j];
    float q = rintf(t / s_w);
    q = fminf(fmaxf(q, -QMAXF), QMAXF);
    qWp[idx] = (signed char)(int)q;
}

// K-D: FUSED quant+GEMM v3. Block = 256(M) x 64(N = 1 out row), 512 thr, 8 waves
// (32-row M-strips, acc[2][4] in AGPR). Thread = (pixel=lane, 16-ch chunk=wave).
// x rows loaded ONCE per kh-group (prefetched a group ahead); kw shift realized as
// the ds_write ROW address (no shfl). Bs double-buffered, XOR 16B-chunk swizzle,
// ONE barrier per tap. A-fragments global->VGPR (L2-hot), prefetched one tap ahead.
__global__ __launch_bounds__(512, 4) void k_gemm(const signed char* __restrict__ qWp,
                                                 const float* __restrict__ x,
                                                 const float* __restrict__ qmul,
                                                 const float* __restrict__ scalars,
                                                 const float* __restrict__ bias,
                                                 float* __restrict__ out) {
    __shared__ __align__(16) signed char Bs[2][64 * 128];  // 2 x 8 KB
    __shared__ float qm[KK];                               // permuted qmul [tap][c]
    const int tid = threadIdx.x;
    const int lane = tid & 63, wv = tid >> 6;              // 8 waves
    const int b  = blockIdx.x >> 6;
    const int oh = blockIdx.x & 63;
    const float* xb = x + (size_t)b * (C_IN * NPIX);
    const int c0 = wv * 16;                                // thread's channel chunk

    for (int i = tid; i < KK; i += 512) {
        int tap = i >> 7, c = i & 127;
        qm[i] = qmul[c * 9 + tap];
    }

    // A addressing: row = wv*32 + mt*16 + (lane&15); 16B chunk (lane>>4) of K=64 half h
    const signed char* aBase = qWp + (size_t)(wv * 32 + (lane & 15)) * KK + (lane >> 4) * 16;

    v4i acc[2][4];
#pragma unroll
    for (int i = 0; i < 2; i++)
#pragma unroll
        for (int jq = 0; jq < 4; jq++) acc[i][jq] = (v4i){0, 0, 0, 0};

    // preload: x row for kh-group 0 (ih = oh-1), A fragments for tap 0
    float xr[16], xrn[16];
    {
        const bool ok = oh >= 1;
        const float* s = xb + (oh - 1) * 64 + lane;
#pragma unroll
        for (int d = 0; d < 16; d++) xr[d] = ok ? s[(size_t)(c0 + d) * NPIX] : 0.f;
    }
    v4i af[2][2], afn[2][2];
#pragma unroll
    for (int h = 0; h < 2; h++)
#pragma unroll
        for (int mt = 0; mt < 2; mt++)
            af[h][mt] = *(const v4i*)(aBase + (size_t)mt * 16 * KK + 0 * 128 + h * 64);

    __syncthreads();   // qm ready

#pragma unroll
    for (int tap = 0; tap < 9; tap++) {
        const int g  = (tap * 11) >> 5;      // kh = tap/3
        const int jj = tap - g * 3;          // kw
        const int s  = jj - 1;               // horizontal shift -1/0/+1
        const bool rowok = ((unsigned)(oh - 1 + g)) < 64u;
        signed char* bsp = (signed char*)Bs[tap & 1];

        // ---- produce Bs(tap): thread's value belongs to output pixel n = lane - s ----
        {
            int n = lane - s;
            bool valid = (unsigned)n < 64u;
            int wrow = valid ? n : (s == -1 ? 0 : 63);   // edge lane fills the zero row
            bool live = rowok && valid;
            const float* qmt = qm + tap * 128 + c0;
            int pk[4];
#pragma unroll
            for (int d4 = 0; d4 < 4; d4++) {
                int w = 0;
#pragma unroll
                for (int e = 0; e < 4; e++) {
                    float v = live ? xr[d4 * 4 + e] : 0.f;
                    float q = rintf(v * qmt[d4 * 4 + e]);
                    q = fminf(fmaxf(q, -QMAXF), QMAXF);
                    w |= ((int)q & 255) << (8 * e);
                }
                pk[d4] = w;
            }
            *(v4i*)(bsp + wrow * 128 + ((wv ^ (wrow & 7)) * 16)) = (v4i){pk[0], pk[1], pk[2], pk[3]};
        }

        // ---- prefetch next kh-group's x row (issued once per group, ~3-tap window) ----
        if (jj == 0 && g < 2) {
            const bool ok = (unsigned)(oh + g) < 64u;
            const float* sp = xb + (oh + g) * 64 + lane;
#pragma unroll
            for (int d = 0; d < 16; d++) xrn[d] = ok ? sp[(size_t)(c0 + d) * NPIX] : 0.f;
        }

        __syncthreads();   // Bs(tap) ready; dbuf covers WAR vs tap-2 reads

        // ---- prefetch A fragments for tap+1 (hidden behind MFMA + next produce) ----
        if (tap < 8) {
#pragma unroll
            for (int h = 0; h < 2; h++)
#pragma unroll
                for (int mt = 0; mt < 2; mt++)
                    afn[h][mt] = *(const v4i*)(aBase + (size_t)mt * 16 * KK + (tap + 1) * 128 + h * 64);
        }

        // ---- MFMA: two K=64 substeps ----
#pragma unroll
        for (int h = 0; h < 2; h++) {
            const int q4 = h * 4 + (lane >> 4);
            v4i bf[4];
#pragma unroll
            for (int nt = 0; nt < 4; nt++) {
                int rb = nt * 16 + (lane & 15);
                bf[nt] = *(const v4i*)(bsp + rb * 128 + ((q4 ^ (rb & 7)) * 16));
            }
#pragma unroll
            for (int mt = 0; mt < 2; mt++)
#pragma unroll
                for (int nt = 0; nt < 4; nt++)
                    acc[mt][nt] = __builtin_amdgcn_mfma_i32_16x16x64_i8(af[h][mt], bf[nt], acc[mt][nt], 0, 0, 0);
        }

        // rotate prefetch regs (renamed under full unroll)
        if (tap < 8) {
#pragma unroll
            for (int h = 0; h < 2; h++)
#pragma unroll
                for (int mt = 0; mt < 2; mt++) af[h][mt] = afn[h][mt];
        }
        if (jj == 2 && g < 2) {
#pragma unroll
            for (int d = 0; d < 16; d++) xr[d] = xrn[d];
        }
    }

    const float ssp = scalars[2];
    const int quad = lane >> 4, col = lane & 15;
    float bv[2][4];
#pragma unroll
    for (int mt = 0; mt < 2; mt++)
#pragma unroll
        for (int rg = 0; rg < 4; rg++)
            bv[mt][rg] = bias[wv * 32 + mt * 16 + quad * 4 + rg];

    float* obase = out + ((size_t)b * C_OUT) * NPIX + oh * 64;
#pragma unroll
    for (int mt = 0; mt < 2; mt++) {
#pragma unroll
        for (int nt = 0; nt < 4; nt++) {
            int n = nt * 16 + col;
#pragma unroll
            for (int rg = 0; rg < 4; rg++) {
                int m = wv * 32 + mt * 16 + quad * 4 + rg;   // c_out
                obase[(size_t)m * NPIX + n] = (float)acc[mt][nt][rg] * ssp + bv[mt][rg];
            }
        }
    }
}

extern "C" void kernel_launch(void* const* d_in, const int* in_sizes, int n_in,
                              void* d_out, int out_size, void* d_ws, size_t ws_size,
                              hipStream_t stream) {
    const float* x    = (const float*)d_in[0];
    const float* wgt  = (const float*)d_in[1];
    const float* bias = (const float*)d_in[2];
    float* out = (float*)d_out;

    char* ws = (char*)d_ws;
    signed char* qWp = (signed char*)(ws + OFF_QW);
    float* w_part    = (float*)(ws + OFF_QW);     // aliases qWp (read before qWp write)
    float* scale     = (float*)(ws + OFF_SCALE);
    float* qmul      = (float*)(ws + OFF_QMUL);
    float* act_part  = (float*)(ws + OFF_APART);
    float* scalars   = (float*)(ws + OFF_SCAL);

    k_prep<<<1104, 256, 0, stream>>>(x, wgt, act_part, w_part);
    k_scales<<<1, 1024, 0, stream>>>(act_part, w_part, scale, qmul, scalars);
    k_quant_w<<<(C_OUT * KK) / 256, 256, 0, stream>>>(wgt, scale, scalars, qWp);
    k_gemm<<<BS * 64, 512, 0, stream>>>(qWp, x, qmul, scalars, bias, out);
}